// Round 4
// baseline (39.208 us; speedup 1.0000x reference)
//
#include <hip/hip_runtime.h>
#include <math.h>

typedef float f2 __attribute__((ext_vector_type(2)));

#define HH 32
#define WW 32
#define PAD 34          // padded scalar r plane
#define PADW 34         // padded width (f2 units) of the shifted pair plane
#define VROWS 17        // shifted pair rows r=0..16 : {v[2r-1], v[2r]}
#define CHQ 10
#define SBS 10
#define KITERS 40

// packed f32 fma, weight pair in %2, broadcast LOW half to both lanes
static __device__ __forceinline__ double pkfma_lo(double a, double w, double c) {
    double d;
    asm("v_pk_fma_f32 %0, %1, %2, %3 op_sel:[0,0,0] op_sel_hi:[1,0,1]"
        : "=v"(d) : "v"(a), "v"(w), "v"(c));
    return d;
}
// broadcast HIGH half of weight pair to both lanes
static __device__ __forceinline__ double pkfma_hi(double a, double w, double c) {
    double d;
    asm("v_pk_fma_f32 %0, %1, %2, %3 op_sel:[0,1,0] op_sel_hi:[1,1,1]"
        : "=v"(d) : "v"(a), "v"(w), "v"(c));
    return d;
}
static __device__ __forceinline__ double dmax2(double a, double b) {
    f2 af = __builtin_bit_cast(f2, a), bf = __builtin_bit_cast(f2, b);
    f2 r; r.x = fmaxf(af.x, bf.x); r.y = fmaxf(af.y, bf.y);
    return __builtin_bit_cast(double, r);
}

__global__ __launch_bounds__(256) void vin_kernel(
    const float* __restrict__ X,     // (bs,2,32,32)
    const int*   __restrict__ S1,    // (bs,10)
    const int*   __restrict__ S2,    // (bs,10)
    const float* __restrict__ bias,  // (150)
    const float* __restrict__ w0,    // (150,2,3,3)
    const float* __restrict__ w1,    // (150)
    const float* __restrict__ w,     // (10,1,3,3)
    const float* __restrict__ wfb,   // (10,1,3,3)
    const float* __restrict__ wo,    // (8,10)
    float* __restrict__ out,         // bs*10*8 output, then bs*10*8 softmax
    int bs)
{
    __shared__ float r_lds[PAD * PAD];
    __shared__ f2    vbuf[2][VROWS * PADW];   // shifted pair planes (ping-pong)
    __shared__ float weff[19];
    __shared__ float wpart[152];

    const int tid = threadIdx.x;
    const int b   = blockIdx.x;

    // ---- zero LDS (halo rows/cols stay zero = SAME padding) ----
    for (int i = tid; i < PAD * PAD; i += 256) r_lds[i] = 0.f;
    {
        const f2 z = (f2)(0.f);
        for (int i = tid; i < 2 * VROWS * PADW; i += 256) (&vbuf[0][0])[i] = z;
    }

    // ---- collapse (w0,bias) x w1 into an effective 2ch 3x3 conv ----
    if (tid < 152) {
        const int o = tid >> 3;
        const int p = tid & 7;
        float s = 0.f;
        if (o < 18) {
            for (int c = p; c < 150; c += 8) s += w1[c] * w0[c * 18 + o];
        } else {
            for (int c = p; c < 150; c += 8) s += w1[c] * bias[c];
        }
        wpart[tid] = s;
    }
    __syncthreads();
    if (tid < 19) {
        float s = 0.f;
        #pragma unroll
        for (int p = 0; p < 8; ++p) s += wpart[tid * 8 + p];
        weff[tid] = s;
    }
    __syncthreads();

    // ---- thread -> 4 consecutive rows (4s..4s+3) of column x ----
    const int x  = tid & 31;
    const int s  = tid >> 5;                 // 0..7
    const int y0 = s * 4;
    const int cx = x + 1;
    const int i0 = (2 * s) * PADW + cx;      // pair {4s-1, 4s}
    const int i1 = i0 + PADW;                // pair {4s+1, 4s+2}
    const int i2 = i1 + PADW;                // pair {4s+3, 4s+4}

    float we[19];
    #pragma unroll
    for (int i = 0; i < 19; ++i) we[i] = weff[i];

    // ---- r = conv(X, w_eff) + b_eff for own 4 rows ----
    const float* Xb = X + (size_t)b * 2 * HH * WW;
    float rr[4];
    #pragma unroll
    for (int dy = 0; dy < 4; ++dy) {
        const int y = y0 + dy;
        float acc = we[18];
        #pragma unroll
        for (int ci = 0; ci < 2; ++ci)
        #pragma unroll
        for (int ky = 0; ky < 3; ++ky)
        #pragma unroll
        for (int kx = 0; kx < 3; ++kx) {
            const int yy = y + ky - 1, xx = x + kx - 1;
            const float xv = (yy >= 0 && yy < HH && xx >= 0 && xx < WW)
                           ? Xb[ci * (HH * WW) + yy * WW + xx] : 0.f;
            acc += we[ci * 9 + ky * 3 + kx] * xv;
        }
        rr[dy] = acc;
        r_lds[(y + 1) * PAD + cx] = acc;
    }

    // stage r as shifted pairs in vbuf[1]
    vbuf[1][i0].y = rr[0];
    { f2 rp; rp.x = rr[1]; rp.y = rr[2]; vbuf[1][i1] = rp; }
    vbuf[1][i2].x = rr[3];
    __syncthreads();

    // ---- packed weight pairs ----
    double WQ[45], WF[45];
    #pragma unroll
    for (int p = 0; p < 45; ++p) WQ[p] = ((const double*)w)[p];
    #pragma unroll
    for (int p = 0; p < 45; ++p) WF[p] = ((const double*)wfb)[p];

    double P0, P1;                 // own pairs {4s,4s+1}, {4s+2,4s+3}
    {
        f2 t0; t0.x = rr[0]; t0.y = rr[1]; P0 = __builtin_bit_cast(double, t0);
        f2 t1; t1.x = rr[2]; t1.y = rr[3]; P1 = __builtin_bit_cast(double, t1);
    }

    // neighborhood load: 9 ds_read_b64 from one plane + 4 shuffle-movs
#define LOADNB(SRC)                                                       \
    double ra[3], rb[3], rc[3], c0[3], c1[3];                             \
    {                                                                     \
        _Pragma("unroll")                                                 \
        for (int j = 0; j < 3; ++j) {                                     \
            const f2 aq = vbuf[SRC][i0 + j - 1];                          \
            const f2 bq = vbuf[SRC][i1 + j - 1];                          \
            const f2 cq = vbuf[SRC][i2 + j - 1];                          \
            ra[j] = __builtin_bit_cast(double, aq);                       \
            rb[j] = __builtin_bit_cast(double, bq);                       \
            rc[j] = __builtin_bit_cast(double, cq);                       \
            if (j != 1) {                                                 \
                c0[j] = __builtin_bit_cast(double,                        \
                          __builtin_shufflevector(aq, bq, 1, 2));         \
                c1[j] = __builtin_bit_cast(double,                        \
                          __builtin_shufflevector(bq, cq, 1, 2));         \
            }                                                             \
        }                                                                 \
        c0[1] = P0; c1[1] = P1;                                           \
    }

#define CONV_BODY(Wp, T0INIT, T1INIT, POST)                               \
    double vm0, vm1;                                                      \
    _Pragma("unroll")                                                     \
    for (int oc = 0; oc < CHQ; ++oc) {                                    \
        double t0 = T0INIT, t1 = T1INIT;                                  \
        _Pragma("unroll")                                                 \
        for (int ky = 0; ky < 3; ++ky)                                    \
        _Pragma("unroll")                                                 \
        for (int j = 0; j < 3; ++j) {                                     \
            const int k = oc * 9 + ky * 3 + j;                            \
            const double o0 = (ky == 0) ? ra[j] : (ky == 1) ? c0[j] : rb[j]; \
            const double o1 = (ky == 0) ? rb[j] : (ky == 1) ? c1[j] : rc[j]; \
            if (k & 1) { t0 = pkfma_hi(o0, Wp[k >> 1], t0);               \
                         t1 = pkfma_hi(o1, Wp[k >> 1], t1); }             \
            else       { t0 = pkfma_lo(o0, Wp[k >> 1], t0);               \
                         t1 = pkfma_lo(o1, Wp[k >> 1], t1); }             \
        }                                                                 \
        POST;                                                             \
        if (oc == 0) { vm0 = t0; vm1 = t1; }                              \
        else { vm0 = dmax2(vm0, t0); vm1 = dmax2(vm1, t1); }              \
    }

#define WRITE_V(DST)                                                      \
    {                                                                     \
        const f2 v0f = __builtin_bit_cast(f2, vm0);                       \
        const f2 v1f = __builtin_bit_cast(f2, vm1);                       \
        vbuf[DST][i0].y = v0f.x;                                          \
        f2 mid; mid.x = v0f.y; mid.y = v1f.x;                             \
        vbuf[DST][i1] = mid;                                              \
        vbuf[DST][i2].x = v1f.y;                                          \
        P0 = vm0; P1 = vm1;                                               \
    }

    // ---- qr = conv(r, w) packed (reads r pairs from vbuf[1]); v0 -> vbuf[0]
    double qr0[CHQ], qr1[CHQ];
    {
        LOADNB(1);
        CONV_BODY(WQ, 0.0, 0.0, { qr0[oc] = t0; qr1[oc] = t1; });
        WRITE_V(0);
        __syncthreads();
    }

#define STEP(SRC, DST) do {                                               \
        LOADNB(SRC);                                                      \
        CONV_BODY(WF, qr0[oc], qr1[oc], {});                              \
        WRITE_V(DST);                                                     \
        __syncthreads();                                                  \
    } while (0)

    // 39 steps: 19 x (0->1, 1->0) + final 0->1; result in vbuf[1]
    #pragma unroll 1
    for (int itp = 0; itp < 19; ++itp) {
        STEP(0, 1);
        STEP(1, 0);
    }
    STEP(0, 1);

    // ---- final q at the 10 gather points; 10->8 matmul + softmax ----
    if (tid < SBS) {
        const int row = b * SBS + tid;
        const int s1 = S1[row];
        const int s2 = S2[row];

        float fq[CHQ];
        #pragma unroll
        for (int oc = 0; oc < CHQ; ++oc) {
            float t = 0.f;
            #pragma unroll
            for (int ky = 0; ky < 3; ++ky)
            #pragma unroll
            for (int kx = 0; kx < 3; ++kx) {
                const int yy = s1 + ky - 1;            // -1..32
                const int xx = s2 + kx - 1;            // -1..32
                const int rp = (yy + 1) >> 1;          // shifted pair row
                const int comp = (yy & 1) ^ 1;         // even row -> .y
                const float vv = vbuf[1][rp * PADW + (xx + 1)][comp];
                t += w[oc * 9 + ky * 3 + kx]   * r_lds[(yy + 1) * PAD + (xx + 1)]
                   + wfb[oc * 9 + ky * 3 + kx] * vv;
            }
            fq[oc] = t;
        }

        float o8[8];
        float mx = -1e30f;
        #pragma unroll
        for (int o = 0; o < 8; ++o) {
            float t = 0.f;
            #pragma unroll
            for (int oc = 0; oc < CHQ; ++oc) t += fq[oc] * wo[o * 10 + oc];
            o8[o] = t;
            mx = fmaxf(mx, t);
        }
        float e[8];
        float es = 0.f;
        #pragma unroll
        for (int o = 0; o < 8; ++o) { e[o] = expf(o8[o] - mx); es += e[o]; }
        const float inv = 1.f / es;

        #pragma unroll
        for (int o = 0; o < 8; ++o) {
            out[(size_t)row * 8 + o] = o8[o];
            out[(size_t)bs * SBS * 8 + (size_t)row * 8 + o] = e[o] * inv;
        }
    }
}

extern "C" void kernel_launch(void* const* d_in, const int* in_sizes, int n_in,
                              void* d_out, int out_size, void* d_ws, size_t ws_size,
                              hipStream_t stream) {
    const float* X    = (const float*)d_in[0];
    const int*   S1   = (const int*)d_in[1];
    const int*   S2   = (const int*)d_in[2];
    const float* bias = (const float*)d_in[3];
    const float* w0   = (const float*)d_in[4];
    const float* w1   = (const float*)d_in[5];
    const float* w    = (const float*)d_in[6];
    const float* wfb  = (const float*)d_in[7];
    const float* wo   = (const float*)d_in[8];
    float* out        = (float*)d_out;

    const int bs = in_sizes[0] / (2 * HH * WW);   // 256

    vin_kernel<<<bs, 256, 0, stream>>>(X, S1, S2, bias, w0, w1, w, wfb, wo, out, bs);
}